// Round 2
// 17594.124 us; speedup vs baseline: 1.5831x; 1.5831x over previous
//
#include <hip/hip_runtime.h>
#include <cmath>

// Problem dims
#define B_  32
#define T_  512
#define D_  512
#define Q_  1024
#define G_  4096   // 4*Q
#define TC  32     // timestep chunk
#define NCHUNK (T_/TC)

// ---------------------------------------------------------------------------
// zero a float region
__global__ void zero_kernel(float* __restrict__ p, int n) {
    int i = blockIdx.x * blockDim.x + threadIdx.x;
    if (i < n) p[i] = 0.f;
}

// ---------------------------------------------------------------------------
// pre[m, n] = sum_k A[row(m), k] * W[n, k] + bih[n] + bhh[n]
// m in [0,1024): m = b*TC + tt ; A row = b*TA + t0 + tt (row-major, stride K)
// W is [4096, K] row-major. pre is [1024, 4096] (i.e. [B][TC][G]).
// BM=BN=128, BK=16, 256 threads, 8x8 micro-tile.
__global__ __launch_bounds__(256) void gemm_pre(
    const float* __restrict__ A, const float* __restrict__ W,
    const float* __restrict__ bih, const float* __restrict__ bhh,
    float* __restrict__ pre, int K, int TA, int t0)
{
    __shared__ __align__(16) float As[16][132];
    __shared__ __align__(16) float Bs[16][132];
    const int tid = threadIdx.x;
    const int tx = tid & 15, ty = tid >> 4;
    const int m0 = blockIdx.y * 128, n0 = blockIdx.x * 128;

    float acc[8][8];
#pragma unroll
    for (int i = 0; i < 8; ++i)
#pragma unroll
        for (int j = 0; j < 8; ++j) acc[i][j] = 0.f;

    for (int k0 = 0; k0 < K; k0 += 16) {
#pragma unroll
        for (int r = 0; r < 2; ++r) {
            int idx = tid + r * 256;          // 0..511
            int row = idx >> 2;               // 0..127
            int kq  = (idx & 3) << 2;         // 0,4,8,12
            int m = m0 + row;
            int bb = m >> 5, tt = m & 31;     // TC == 32
            const float* ap = A + (size_t)(bb * TA + t0 + tt) * K + k0 + kq;
            float4 av = *(const float4*)ap;
            As[kq + 0][row] = av.x; As[kq + 1][row] = av.y;
            As[kq + 2][row] = av.z; As[kq + 3][row] = av.w;
            const float* wp = W + (size_t)(n0 + row) * K + k0 + kq;
            float4 wv = *(const float4*)wp;
            Bs[kq + 0][row] = wv.x; Bs[kq + 1][row] = wv.y;
            Bs[kq + 2][row] = wv.z; Bs[kq + 3][row] = wv.w;
        }
        __syncthreads();
#pragma unroll
        for (int k = 0; k < 16; ++k) {
            float a[8], bv[8];
#pragma unroll
            for (int i = 0; i < 8; ++i) a[i] = As[k][ty * 8 + i];
#pragma unroll
            for (int j = 0; j < 4; ++j) {
                bv[j]     = Bs[k][tx * 4 + j];
                bv[4 + j] = Bs[k][64 + tx * 4 + j];
            }
#pragma unroll
            for (int i = 0; i < 8; ++i)
#pragma unroll
                for (int j = 0; j < 8; ++j)
                    acc[i][j] = fmaf(a[i], bv[j], acc[i][j]);
        }
        __syncthreads();
    }

    const int n1 = n0 + tx * 4;
    const int n2 = n0 + 64 + tx * 4;
    float bias1[4], bias2[4];
#pragma unroll
    for (int j = 0; j < 4; ++j) {
        bias1[j] = bih[n1 + j] + bhh[n1 + j];
        bias2[j] = bih[n2 + j] + bhh[n2 + j];
    }
#pragma unroll
    for (int i = 0; i < 8; ++i) {
        int m = m0 + ty * 8 + i;
        float* prow = pre + (size_t)m * G_;
        float4 o1, o2;
        o1.x = acc[i][0] + bias1[0]; o1.y = acc[i][1] + bias1[1];
        o1.z = acc[i][2] + bias1[2]; o1.w = acc[i][3] + bias1[3];
        o2.x = acc[i][4] + bias2[0]; o2.y = acc[i][5] + bias2[1];
        o2.z = acc[i][6] + bias2[2]; o2.w = acc[i][7] + bias2[3];
        *(float4*)(prow + n1) = o1;
        *(float4*)(prow + n2) = o2;
    }
}

// ---------------------------------------------------------------------------
// One LSTM timestep, zero LDS. 512 WGs x 256 threads; WG owns q in
// [2*wg, 2*wg+2). Thread (bg,ql,sl):
//   sl = tid&31  : k-slice, k in { m*128 + sl*4 + 0..3 : m=0..7 }
//   ql = bit 5   : which of the WG's 2 q columns
//   bg = tid>>6  : b-group (8 batches each)
// The thread's 4 gate rows x 32 k of whh live in 128 VGPRs (loaded once per
// launch, L3-resident). h is read straight from global (float4; the two
// ql-halves of a wave read the same 32 addresses -> one 512B fetch, h is
// 128 KB so L2-resident). Partials reduced with a 5-level butterfly
// reduce-scatter over sl; lane sl ends owning gate (sl&3) of batch
// bg*8+(sl>>2). Lanes with (sl&3)==0 do the pointwise cell update.
__global__ __launch_bounds__(256, 2) void lstm_step_reg(
    const float* __restrict__ pre, int tt,
    const float* __restrict__ whh,
    const float* __restrict__ h_in, float* __restrict__ h_out,
    float* __restrict__ c_st,
    float* __restrict__ yout, int yT, int yt)
{
    const int tid = threadIdx.x;
    const int sl = tid & 31;
    const int ql = (tid >> 5) & 1;
    const int bg = tid >> 6;              // 0..3
    const int q  = blockIdx.x * 2 + ql;

    // preload weights: w[cc][m] = whh[(cc*Q + q)*Q + m*128 + sl*4 .. +3]
    float4 w[4][8];
#pragma unroll
    for (int cc = 0; cc < 4; ++cc) {
        const float* wrow = whh + (size_t)(cc * Q_ + q) * Q_ + sl * 4;
#pragma unroll
        for (int m = 0; m < 8; ++m)
            w[cc][m] = *(const float4*)(wrow + m * 128);
    }

    float cur[32];
#pragma unroll
    for (int j = 0; j < 32; ++j) cur[j] = 0.f;

#pragma unroll
    for (int m = 0; m < 8; ++m) {
        float4 hv[8];
#pragma unroll
        for (int i = 0; i < 8; ++i)
            hv[i] = *(const float4*)(h_in + (size_t)(bg * 8 + i) * Q_
                                     + m * 128 + sl * 4);
#pragma unroll
        for (int i = 0; i < 8; ++i)
#pragma unroll
            for (int cc = 0; cc < 4; ++cc) {
                float4 wv = w[cc][m];
                float a = cur[i * 4 + cc];
                a = fmaf(hv[i].x, wv.x, a);
                a = fmaf(hv[i].y, wv.y, a);
                a = fmaf(hv[i].z, wv.z, a);
                a = fmaf(hv[i].w, wv.w, a);
                cur[i * 4 + cc] = a;
            }
    }

    // butterfly reduce-scatter over sl (within each 32-lane half).
    // After level MASK, surviving index bit == lane bit; lane sl ends with
    // cur[0] = full K-sum of original index sl (= (sl>>2)*4 + (sl&3)).
#define RED_LEVEL(MASK)                                                   \
    {                                                                     \
        const bool hi = (sl & MASK) != 0;                                 \
        _Pragma("unroll")                                                 \
        for (int j = 0; j < MASK; ++j) {                                  \
            float keep = hi ? cur[j + MASK] : cur[j];                     \
            float send = hi ? cur[j] : cur[j + MASK];                     \
            cur[j] = keep + __shfl_xor(send, MASK, 32);                   \
        }                                                                 \
    }
    RED_LEVEL(16) RED_LEVEL(8) RED_LEVEL(4) RED_LEVEL(2) RED_LEVEL(1)
#undef RED_LEVEL

    const int i_out  = sl >> 2;           // b offset within group
    const int cc_out = sl & 3;            // gate index
    const int b_out  = bg * 8 + i_out;

    float gate = cur[0]
               + pre[((size_t)b_out * TC + tt) * G_ + cc_out * Q_ + q];

    // gather the 4 gates of (b_out, q) from the 4-lane group
    const int base = sl & ~3;
    float gi = __shfl(gate, base + 0, 32);
    float gf = __shfl(gate, base + 1, 32);
    float gg = __shfl(gate, base + 2, 32);
    float go = __shfl(gate, base + 3, 32);

    if (cc_out == 0) {
        float i_ = 1.f / (1.f + expf(-gi));
        float f_ = 1.f / (1.f + expf(-gf));
        float g_ = tanhf(gg);
        float o_ = 1.f / (1.f + expf(-go));
        float c_old = c_st[b_out * Q_ + q];
        float c_new = f_ * c_old + i_ * g_;
        float h_new = o_ * tanhf(c_new);
        c_st[b_out * Q_ + q] = c_new;
        h_out[b_out * Q_ + q] = h_new;
        yout[((size_t)b_out * yT + yt) * Q_ + q] = h_new;
    }
}

// ---------------------------------------------------------------------------
__global__ void copy_hc(const float* __restrict__ h, const float* __restrict__ c,
                        float* __restrict__ dst)
{
    int i = blockIdx.x * blockDim.x + threadIdx.x;   // 0..65535
    if (i < 32768) dst[i] = h[i];
    else           dst[i] = c[i - 32768];
}

// ---------------------------------------------------------------------------
extern "C" void kernel_launch(void* const* d_in, const int* in_sizes, int n_in,
                              void* d_out, int out_size, void* d_ws, size_t ws_size,
                              hipStream_t stream)
{
    const float* x    = (const float*)d_in[0];  // [32,512,512]
    const float* wih0 = (const float*)d_in[1];  // [4096,512]
    const float* whh0 = (const float*)d_in[2];  // [4096,1024]
    const float* bih0 = (const float*)d_in[3];
    const float* bhh0 = (const float*)d_in[4];
    const float* wih1 = (const float*)d_in[5];  // [4096,1024]
    const float* whh1 = (const float*)d_in[6];  // [4096,1024]
    const float* bih1 = (const float*)d_in[7];
    const float* bhh1 = (const float*)d_in[8];
    float* out = (float*)d_out;                  // y1 [32,512,1024] ++ h[32,1024] ++ c[32,1024]
    float* ws  = (float*)d_ws;

    float* pre0 = ws;                  // 4,194,304 floats  ([B][TC][4096])
    float* pre1 = ws + 4194304;        // 4,194,304
    float* y0c  = ws + 8388608;        // 1,048,576  ([B][TC][1024])
    float* st   = ws + 9437184;        // states: 6 x 32768
    float* h0a = st;            float* h0b = st + 32768;
    float* c0  = st + 65536;
    float* h1a = st + 98304;    float* h1b = st + 131072;
    float* c1  = st + 163840;          // total ws = 9,633,792 floats (~38.5 MB)

    // zero all state buffers (ws is poisoned 0xAA before every call)
    hipLaunchKernelGGL(zero_kernel, dim3(768), dim3(256), 0, stream, st, 196608);

    for (int ch = 0; ch < NCHUNK; ++ch) {
        const int t0 = ch * TC;
        // layer-0 input projection for this chunk: x slice -> pre0
        hipLaunchKernelGGL(gemm_pre, dim3(32, 8), dim3(256), 0, stream,
                           x, wih0, bih0, bhh0, pre0, 512, 512, t0);
        for (int tt = 0; tt < TC; ++tt) {
            const int t = t0 + tt;
            const float* hin = (t & 1) ? h0b : h0a;
            float* hout      = (t & 1) ? h0a : h0b;
            hipLaunchKernelGGL(lstm_step_reg, dim3(512), dim3(256), 0, stream,
                               pre0, tt, whh0, hin, hout, c0, y0c, TC, tt);
        }
        // layer-1 input projection for this chunk: y0c -> pre1
        hipLaunchKernelGGL(gemm_pre, dim3(32, 8), dim3(256), 0, stream,
                           y0c, wih1, bih1, bhh1, pre1, 1024, 32, 0);
        for (int tt = 0; tt < TC; ++tt) {
            const int t = t0 + tt;
            const float* hin = (t & 1) ? h1b : h1a;
            float* hout      = (t & 1) ? h1a : h1b;
            hipLaunchKernelGGL(lstm_step_reg, dim3(512), dim3(256), 0, stream,
                               pre1, tt, whh1, hin, hout, c1, out, T_, t);
        }
    }
    // final (h, c) tail: T=512 even -> last write went to the 'a' buffer
    hipLaunchKernelGGL(copy_hc, dim3(256), dim3(256), 0, stream,
                       h1a, c1, out + 16777216);
}

// Round 3
// 15120.279 us; speedup vs baseline: 1.8421x; 1.1636x over previous
//
#include <hip/hip_runtime.h>
#include <cmath>

// Problem dims
#define B_  32
#define T_  512
#define D_  512
#define Q_  1024
#define G_  4096   // 4*Q
#define TC  32     // timestep chunk
#define NCHUNK (T_/TC)

typedef short bf16x8 __attribute__((ext_vector_type(8)));
typedef float f32x4  __attribute__((ext_vector_type(4)));

__device__ __forceinline__ unsigned short f2bf(float f) {
    unsigned u = __float_as_uint(f);
    return (unsigned short)((u + 0x7FFFu + ((u >> 16) & 1u)) >> 16);
}

// ---------------------------------------------------------------------------
__global__ void zero_kernel(float* __restrict__ p, int n) {
    int i = blockIdx.x * blockDim.x + threadIdx.x;
    if (i < n) p[i] = 0.f;
}

// ---------------------------------------------------------------------------
// generic fp32 -> bf16 (RNE), n4 = n/4
__global__ void convert_bf16(const float* __restrict__ src,
                             unsigned short* __restrict__ dst, int n4) {
    int i = blockIdx.x * blockDim.x + threadIdx.x;
    int stride = gridDim.x * blockDim.x;
    for (; i < n4; i += stride) {
        float4 v = ((const float4*)src)[i];
        ushort4 o;
        o.x = f2bf(v.x); o.y = f2bf(v.y); o.z = f2bf(v.z); o.w = f2bf(v.w);
        ((ushort4*)dst)[i] = o;
    }
}

// ---------------------------------------------------------------------------
// x chunk -> bf16, remapped to [m][k] with m = b*TC + tt (row b*T_+t0+tt of x)
__global__ void convert_x_chunk(const float* __restrict__ x,
                                unsigned short* __restrict__ dst, int t0) {
    int i = blockIdx.x * blockDim.x + threadIdx.x;   // 131072 threads
    int m  = i >> 7;              // 128 float4 per 512-wide row
    int k4 = (i & 127) << 2;
    int b = m >> 5, tt = m & 31;
    float4 v = *(const float4*)(x + (size_t)(b * T_ + t0 + tt) * D_ + k4);
    ushort4 o;
    o.x = f2bf(v.x); o.y = f2bf(v.y); o.z = f2bf(v.z); o.w = f2bf(v.w);
    *(ushort4*)(dst + (size_t)m * D_ + k4) = o;
}

// ---------------------------------------------------------------------------
// bf16 MFMA GEMM: pre[m][n] = sum_k A[m][k]*W[n][k] + bih[n] + bhh[n]
// A: [1024][K] bf16, W: [4096][K] bf16, pre: [1024][4096] fp32.
// 128x128 tile, BK=32, 256 threads = 4 waves (2x2), each wave 64x64 via
// 4x4 frags of mfma_f32_16x16x32_bf16. LDS layout [k8][row] 16B slots ->
// conflict-free ds_read_b128 / ds_write_b128. Reg-staged global loads,
// software-prefetched one K-tile ahead (coalesced 64B per row).
__global__ __launch_bounds__(256) void gemm_bf16(
    const unsigned short* __restrict__ A,
    const unsigned short* __restrict__ W,
    const float* __restrict__ bih, const float* __restrict__ bhh,
    float* __restrict__ pre, int K)
{
    __shared__ short As[4096];   // 8 KB: slot s = k8*128+row, shorts s*8
    __shared__ short Bs[4096];
    const int tid  = threadIdx.x;
    const int lane = tid & 63;
    const int wv   = tid >> 6;            // 0..3
    const int wr   = wv >> 1, wc = wv & 1;
    const int m0 = blockIdx.y * 128, n0 = blockIdx.x * 128;

    f32x4 zero4 = {0.f, 0.f, 0.f, 0.f};
    f32x4 acc[4][4];
#pragma unroll
    for (int i = 0; i < 4; ++i)
#pragma unroll
        for (int j = 0; j < 4; ++j) acc[i][j] = zero4;

    // staging: thread handles slots (sk8,srow) and (sk8+1,srow): 32B of one row
    const int srow = tid >> 1;
    const int sk8  = (tid & 1) << 1;      // 0 or 2
    const unsigned short* aBase = A + (size_t)(m0 + srow) * K + sk8 * 8;
    const unsigned short* wBase = W + (size_t)(n0 + srow) * K + sk8 * 8;

    bf16x8 rA0 = *(const bf16x8*)(aBase);
    bf16x8 rA1 = *(const bf16x8*)(aBase + 8);
    bf16x8 rB0 = *(const bf16x8*)(wBase);
    bf16x8 rB1 = *(const bf16x8*)(wBase + 8);

    const int l15 = lane & 15, l4 = lane >> 4;

    for (int k0 = 0; k0 < K; k0 += 32) {
        __syncthreads();                  // previous compute done, LDS free
        *(bf16x8*)&As[(sk8 * 128 + srow) * 8]       = rA0;
        *(bf16x8*)&As[((sk8 + 1) * 128 + srow) * 8] = rA1;
        *(bf16x8*)&Bs[(sk8 * 128 + srow) * 8]       = rB0;
        *(bf16x8*)&Bs[((sk8 + 1) * 128 + srow) * 8] = rB1;
        __syncthreads();                  // LDS ready
        if (k0 + 32 < K) {                // prefetch next K-tile (hides latency)
            rA0 = *(const bf16x8*)(aBase + k0 + 32);
            rA1 = *(const bf16x8*)(aBase + k0 + 40);
            rB0 = *(const bf16x8*)(wBase + k0 + 32);
            rB1 = *(const bf16x8*)(wBase + k0 + 40);
        }
        bf16x8 af[4], bfr[4];
#pragma unroll
        for (int fm = 0; fm < 4; ++fm)
            af[fm] = *(const bf16x8*)&As[(l4 * 128 + wr * 64 + fm * 16 + l15) * 8];
#pragma unroll
        for (int fn = 0; fn < 4; ++fn)
            bfr[fn] = *(const bf16x8*)&Bs[(l4 * 128 + wc * 64 + fn * 16 + l15) * 8];
#pragma unroll
        for (int fm = 0; fm < 4; ++fm)
#pragma unroll
            for (int fn = 0; fn < 4; ++fn)
                acc[fm][fn] = __builtin_amdgcn_mfma_f32_16x16x32_bf16(
                    af[fm], bfr[fn], acc[fm][fn], 0, 0, 0);
    }

    // epilogue: D row = (lane>>4)*4 + r, col = lane&15  [verified mapping]
#pragma unroll
    for (int fn = 0; fn < 4; ++fn) {
        int n = n0 + wc * 64 + fn * 16 + l15;
        float bias = bih[n] + bhh[n];
#pragma unroll
        for (int fm = 0; fm < 4; ++fm) {
            int mb = m0 + wr * 64 + fm * 16 + l4 * 4;
#pragma unroll
            for (int r = 0; r < 4; ++r)
                pre[(size_t)(mb + r) * G_ + n] = acc[fm][fn][r] + bias;
        }
    }
}

// ---------------------------------------------------------------------------
// One LSTM timestep, zero LDS (unchanged from R2 except optional bf16 y-out).
__global__ __launch_bounds__(256, 2) void lstm_step_reg(
    const float* __restrict__ pre, int tt,
    const float* __restrict__ whh,
    const float* __restrict__ h_in, float* __restrict__ h_out,
    float* __restrict__ c_st,
    float* __restrict__ yout, unsigned short* __restrict__ ybf,
    int yT, int yt)
{
    const int tid = threadIdx.x;
    const int sl = tid & 31;
    const int ql = (tid >> 5) & 1;
    const int bg = tid >> 6;              // 0..3
    const int q  = blockIdx.x * 2 + ql;

    float4 w[4][8];
#pragma unroll
    for (int cc = 0; cc < 4; ++cc) {
        const float* wrow = whh + (size_t)(cc * Q_ + q) * Q_ + sl * 4;
#pragma unroll
        for (int m = 0; m < 8; ++m)
            w[cc][m] = *(const float4*)(wrow + m * 128);
    }

    float cur[32];
#pragma unroll
    for (int j = 0; j < 32; ++j) cur[j] = 0.f;

#pragma unroll
    for (int m = 0; m < 8; ++m) {
        float4 hv[8];
#pragma unroll
        for (int i = 0; i < 8; ++i)
            hv[i] = *(const float4*)(h_in + (size_t)(bg * 8 + i) * Q_
                                     + m * 128 + sl * 4);
#pragma unroll
        for (int i = 0; i < 8; ++i)
#pragma unroll
            for (int cc = 0; cc < 4; ++cc) {
                float4 wv = w[cc][m];
                float a = cur[i * 4 + cc];
                a = fmaf(hv[i].x, wv.x, a);
                a = fmaf(hv[i].y, wv.y, a);
                a = fmaf(hv[i].z, wv.z, a);
                a = fmaf(hv[i].w, wv.w, a);
                cur[i * 4 + cc] = a;
            }
    }

#define RED_LEVEL(MASK)                                                   \
    {                                                                     \
        const bool hi = (sl & MASK) != 0;                                 \
        _Pragma("unroll")                                                 \
        for (int j = 0; j < MASK; ++j) {                                  \
            float keep = hi ? cur[j + MASK] : cur[j];                     \
            float send = hi ? cur[j] : cur[j + MASK];                     \
            cur[j] = keep + __shfl_xor(send, MASK, 32);                   \
        }                                                                 \
    }
    RED_LEVEL(16) RED_LEVEL(8) RED_LEVEL(4) RED_LEVEL(2) RED_LEVEL(1)
#undef RED_LEVEL

    const int i_out  = sl >> 2;
    const int cc_out = sl & 3;
    const int b_out  = bg * 8 + i_out;

    float gate = cur[0]
               + pre[((size_t)b_out * TC + tt) * G_ + cc_out * Q_ + q];

    const int base = sl & ~3;
    float gi = __shfl(gate, base + 0, 32);
    float gf = __shfl(gate, base + 1, 32);
    float gg = __shfl(gate, base + 2, 32);
    float go = __shfl(gate, base + 3, 32);

    if (cc_out == 0) {
        float i_ = 1.f / (1.f + expf(-gi));
        float f_ = 1.f / (1.f + expf(-gf));
        float g_ = tanhf(gg);
        float o_ = 1.f / (1.f + expf(-go));
        float c_old = c_st[b_out * Q_ + q];
        float c_new = f_ * c_old + i_ * g_;
        float h_new = o_ * tanhf(c_new);
        c_st[b_out * Q_ + q] = c_new;
        h_out[b_out * Q_ + q] = h_new;
        if (ybf) ybf[((size_t)b_out * TC + tt) * Q_ + q] = f2bf(h_new);
        else     yout[((size_t)b_out * yT + yt) * Q_ + q] = h_new;
    }
}

// ---------------------------------------------------------------------------
__global__ void copy_hc(const float* __restrict__ h, const float* __restrict__ c,
                        float* __restrict__ dst)
{
    int i = blockIdx.x * blockDim.x + threadIdx.x;   // 0..65535
    if (i < 32768) dst[i] = h[i];
    else           dst[i] = c[i - 32768];
}

// ---------------------------------------------------------------------------
extern "C" void kernel_launch(void* const* d_in, const int* in_sizes, int n_in,
                              void* d_out, int out_size, void* d_ws, size_t ws_size,
                              hipStream_t stream)
{
    const float* x    = (const float*)d_in[0];  // [32,512,512]
    const float* wih0 = (const float*)d_in[1];  // [4096,512]
    const float* whh0 = (const float*)d_in[2];  // [4096,1024]
    const float* bih0 = (const float*)d_in[3];
    const float* bhh0 = (const float*)d_in[4];
    const float* wih1 = (const float*)d_in[5];  // [4096,1024]
    const float* whh1 = (const float*)d_in[6];  // [4096,1024]
    const float* bih1 = (const float*)d_in[7];
    const float* bhh1 = (const float*)d_in[8];
    float* out = (float*)d_out;                  // y1 [32,512,1024] ++ h[32,1024] ++ c[32,1024]
    float* ws  = (float*)d_ws;

    float* pre0 = ws;                                          // 4,194,304 f
    float* pre1 = ws + 4194304;                                // 4,194,304 f
    unsigned short* xbfc  = (unsigned short*)(ws + 8388608);   //   524,288 bf16
    unsigned short* wih0b = (unsigned short*)(ws + 8650752);   // 2,097,152 bf16
    unsigned short* wih1b = (unsigned short*)(ws + 9699328);   // 4,194,304 bf16
    unsigned short* y0cb  = (unsigned short*)(ws + 11796480);  // 1,048,576 bf16
    float* st   = ws + 12320768;                               // 196,608 f
    float* h0a = st;            float* h0b = st + 32768;
    float* c0  = st + 65536;
    float* h1a = st + 98304;    float* h1b = st + 131072;
    float* c1  = st + 163840;   // total ws = 12,517,376 floats (~50 MB)

    // zero state buffers (ws is poisoned before every call)
    hipLaunchKernelGGL(zero_kernel, dim3(768), dim3(256), 0, stream, st, 196608);

    // one-time weight conversions (per call; ~30 us total)
    hipLaunchKernelGGL(convert_bf16, dim3(1024), dim3(256), 0, stream,
                       wih0, wih0b, 2097152 / 4);
    hipLaunchKernelGGL(convert_bf16, dim3(1024), dim3(256), 0, stream,
                       wih1, wih1b, 4194304 / 4);

    for (int ch = 0; ch < NCHUNK; ++ch) {
        const int t0 = ch * TC;

        // layer-0 input projection (bf16 MFMA)
        hipLaunchKernelGGL(convert_x_chunk, dim3(512), dim3(256), 0, stream,
                           x, xbfc, t0);
        hipLaunchKernelGGL(gemm_bf16, dim3(32, 8), dim3(256), 0, stream,
                           xbfc, wih0b, bih0, bhh0, pre0, 512);

        for (int tt = 0; tt < TC; ++tt) {
            const int t = t0 + tt;
            const float* hin = (t & 1) ? h0b : h0a;
            float* hout      = (t & 1) ? h0a : h0b;
            hipLaunchKernelGGL(lstm_step_reg, dim3(512), dim3(256), 0, stream,
                               pre0, tt, whh0, hin, hout, c0,
                               (float*)nullptr, y0cb, TC, tt);
        }

        // layer-1 input projection (bf16 MFMA)
        hipLaunchKernelGGL(gemm_bf16, dim3(32, 8), dim3(256), 0, stream,
                           y0cb, wih1b, bih1, bhh1, pre1, 1024);

        for (int tt = 0; tt < TC; ++tt) {
            const int t = t0 + tt;
            const float* hin = (t & 1) ? h1b : h1a;
            float* hout      = (t & 1) ? h1a : h1b;
            hipLaunchKernelGGL(lstm_step_reg, dim3(512), dim3(256), 0, stream,
                               pre1, tt, whh1, hin, hout, c1,
                               out, (unsigned short*)nullptr, T_, t);
        }
    }

    // final (h, c) tail: T=512 even -> last write went to the 'a' buffer
    hipLaunchKernelGGL(copy_hc, dim3(256), dim3(256), 0, stream,
                       h1a, c1, out + 16777216);
}

// Round 5
// 7570.143 us; speedup vs baseline: 3.6793x; 1.9974x over previous
//
#include <hip/hip_runtime.h>
#include <cmath>

// Problem dims
#define B_  32
#define T_  512
#define D_  512
#define Q_  1024
#define G_  4096   // 4*Q
#define TC  32     // timestep chunk
#define NCHUNK (T_/TC)

typedef short bf16x8 __attribute__((ext_vector_type(8)));
typedef float f32x4  __attribute__((ext_vector_type(4)));

__device__ __forceinline__ unsigned short f2bf(float f) {
    unsigned u = __float_as_uint(f);
    return (unsigned short)((u + 0x7FFFu + ((u >> 16) & 1u)) >> 16);
}

// ---------------------------------------------------------------------------
__global__ void zero_kernel(float* __restrict__ p, int n) {
    int i = blockIdx.x * blockDim.x + threadIdx.x;
    if (i < n) p[i] = 0.f;
}

// ---------------------------------------------------------------------------
// permute + convert: dst[q*4+cc][k] = bf16(src[cc*1024+q][k]); shift=log2(K/4)
__global__ void convert_permute(const float* __restrict__ src,
                                unsigned short* __restrict__ dst,
                                int K, int shift) {
    int i = blockIdx.x * blockDim.x + threadIdx.x;
    int row = i >> shift;
    if (row >= 4096) return;
    int k4 = (i & ((1 << shift) - 1)) << 2;
    int cc = row >> 10, q = row & 1023;
    float4 v = *(const float4*)(src + (size_t)row * K + k4);
    ushort4 o;
    o.x = f2bf(v.x); o.y = f2bf(v.y); o.z = f2bf(v.z); o.w = f2bf(v.w);
    *(ushort4*)(dst + (size_t)(q * 4 + cc) * K + k4) = o;
}

// ---------------------------------------------------------------------------
__global__ void permute_bias(const float* __restrict__ bih,
                             const float* __restrict__ bhh,
                             float* __restrict__ dst) {
    int n = blockIdx.x * blockDim.x + threadIdx.x;   // 0..4095, n' = q*4+cc
    int cc = n & 3, q = n >> 2;
    dst[n] = bih[cc * Q_ + q] + bhh[cc * Q_ + q];
}

// ---------------------------------------------------------------------------
// x chunk -> bf16, remapped to [m][512] with m = b*TC + tt
__global__ void convert_x_chunk(const float* __restrict__ x,
                                unsigned short* __restrict__ dst, int t0) {
    int i = blockIdx.x * blockDim.x + threadIdx.x;   // 131072 threads
    int m  = i >> 7;
    int k4 = (i & 127) << 2;
    int b = m >> 5, tt = m & 31;
    float4 v = *(const float4*)(x + (size_t)(b * T_ + t0 + tt) * D_ + k4);
    ushort4 o;
    o.x = f2bf(v.x); o.y = f2bf(v.y); o.z = f2bf(v.z); o.w = f2bf(v.w);
    *(ushort4*)(dst + (size_t)m * D_ + k4) = o;
}

// ---------------------------------------------------------------------------
// bf16 MFMA GEMM: pre[m][n'] = sum_k A[m][k]*W[n'][k] + biasp[n']
// A: [1024][K] bf16 (m-major), W: [4096][K] bf16 (permuted rows), pre fp32.
// 128x128 tile, BK=32, 4 waves, LDS slot layout [k8][row] (16B slots).
__global__ __launch_bounds__(256) void gemm_bf16(
    const unsigned short* __restrict__ A,
    const unsigned short* __restrict__ W,
    const float* __restrict__ biasp,
    float* __restrict__ pre, int K)
{
    __shared__ short As[4096];
    __shared__ short Bs[4096];
    const int tid  = threadIdx.x;
    const int lane = tid & 63;
    const int wv   = tid >> 6;
    const int wr   = wv >> 1, wc = wv & 1;
    const int m0 = blockIdx.y * 128, n0 = blockIdx.x * 128;

    f32x4 zero4 = {0.f, 0.f, 0.f, 0.f};
    f32x4 acc[4][4];
#pragma unroll
    for (int i = 0; i < 4; ++i)
#pragma unroll
        for (int j = 0; j < 4; ++j) acc[i][j] = zero4;

    const int srow = tid >> 1;
    const int sk8  = (tid & 1) << 1;
    const unsigned short* aBase = A + (size_t)(m0 + srow) * K + sk8 * 8;
    const unsigned short* wBase = W + (size_t)(n0 + srow) * K + sk8 * 8;

    bf16x8 rA0 = *(const bf16x8*)(aBase);
    bf16x8 rA1 = *(const bf16x8*)(aBase + 8);
    bf16x8 rB0 = *(const bf16x8*)(wBase);
    bf16x8 rB1 = *(const bf16x8*)(wBase + 8);

    const int l15 = lane & 15, l4 = lane >> 4;

    for (int k0 = 0; k0 < K; k0 += 32) {
        __syncthreads();
        *(bf16x8*)&As[(sk8 * 128 + srow) * 8]       = rA0;
        *(bf16x8*)&As[((sk8 + 1) * 128 + srow) * 8] = rA1;
        *(bf16x8*)&Bs[(sk8 * 128 + srow) * 8]       = rB0;
        *(bf16x8*)&Bs[((sk8 + 1) * 128 + srow) * 8] = rB1;
        __syncthreads();
        if (k0 + 32 < K) {
            rA0 = *(const bf16x8*)(aBase + k0 + 32);
            rA1 = *(const bf16x8*)(aBase + k0 + 40);
            rB0 = *(const bf16x8*)(wBase + k0 + 32);
            rB1 = *(const bf16x8*)(wBase + k0 + 40);
        }
        bf16x8 af[4], bfr[4];
#pragma unroll
        for (int fm = 0; fm < 4; ++fm)
            af[fm] = *(const bf16x8*)&As[(l4 * 128 + wr * 64 + fm * 16 + l15) * 8];
#pragma unroll
        for (int fn = 0; fn < 4; ++fn)
            bfr[fn] = *(const bf16x8*)&Bs[(l4 * 128 + wc * 64 + fn * 16 + l15) * 8];
#pragma unroll
        for (int fm = 0; fm < 4; ++fm)
#pragma unroll
            for (int fn = 0; fn < 4; ++fn)
                acc[fm][fn] = __builtin_amdgcn_mfma_f32_16x16x32_bf16(
                    af[fm], bfr[fn], acc[fm][fn], 0, 0, 0);
    }

#pragma unroll
    for (int fn = 0; fn < 4; ++fn) {
        int n = n0 + wc * 64 + fn * 16 + l15;
        float bias = biasp[n];
#pragma unroll
        for (int fm = 0; fm < 4; ++fm) {
            int mb = m0 + wr * 64 + fm * 16 + l4 * 4;
#pragma unroll
            for (int r = 0; r < 4; ++r)
                pre[(size_t)(mb + r) * G_ + n] = acc[fm][fn][r] + bias;
        }
    }
}

// ---------------------------------------------------------------------------
// Fused MFMA LSTM step for (up to) two independent layer-steps.
// Grid 256 WGs: blocks 0..127 = slot 0 (layer 0), 128..255 = slot 1 (layer 1).
// Per slot: WG wg owns n' in [wg*32, wg*32+32). A = h (32 b x 1024 k, bf16)
// staged fully in LDS; W rows (n' = q*4+cc permuted) streamed 32k at a time.
// Wave wv: fm = wv&1 (b half), nsub = (wv>>1)*16. 1 MFMA per K-iter.
// Epilogue: gate quad gathered via 4-lane shfl; cc==0 lanes update c (fp32),
// write h bf16 (next step's A) and optionally fp32 y.
__global__ __launch_bounds__(256) void lstm_step_mfma(
    const unsigned short* __restrict__ W0, const float* __restrict__ pre0t,
    const unsigned short* __restrict__ hin0, int hinS0,
    unsigned short* __restrict__ hout0, int houtS0,
    float* __restrict__ c0p, float* __restrict__ y0p,
    const unsigned short* __restrict__ W1, const float* __restrict__ pre1t,
    const unsigned short* __restrict__ hin1, int hinS1,
    unsigned short* __restrict__ hout1, int houtS1,
    float* __restrict__ c1p, float* __restrict__ y1p)
{
    __shared__ __align__(16) short Als[32768];   // 64 KB: slot (k8*32+b)*8
    __shared__ __align__(16) short Bls[1024];    // 2 KB:  slot (ko*32+row)*8

    const unsigned short* Wr; const float* preT; const unsigned short* hin;
    unsigned short* hout; float* cst; float* yf; int hinS, houtS;
    if (blockIdx.x < 128) {
        Wr = W0; preT = pre0t; hin = hin0; hinS = hinS0;
        hout = hout0; houtS = houtS0; cst = c0p; yf = y0p;
    } else {
        Wr = W1; preT = pre1t; hin = hin1; hinS = hinS1;
        hout = hout1; houtS = houtS1; cst = c1p; yf = y1p;
    }
    if (!Wr) return;

    const int tid  = threadIdx.x;
    const int lane = tid & 63;
    const int wv   = tid >> 6;
    const int l15 = lane & 15, l4 = lane >> 4;
    const int n0   = (blockIdx.x & 127) * 32;
    const int nsub = (wv >> 1) * 16;
    const int fm   = wv & 1;

    // stage A (h) fully: 4096 x 16B chunks, coalesced
#pragma unroll
    for (int r = 0; r < 16; ++r) {
        int chunk = r * 256 + tid;        // 0..4095
        int row = chunk >> 7, k8 = chunk & 127;
        bf16x8 v = *(const bf16x8*)(hin + (size_t)row * hinS + k8 * 8);
        *(bf16x8*)&Als[(k8 * 32 + row) * 8] = v;
    }

    // B prefetch (tid<128 stages: row=tid>>2, ko=tid&3)
    const int rowb = tid >> 2, ko = tid & 3;
    bf16x8 rB;
    {
        const unsigned short* bp = (tid < 128)
            ? (Wr + (size_t)(n0 + rowb) * 1024 + ko * 8) : Wr;
        rB = *(const bf16x8*)bp;
    }

    f32x4 acc = {0.f, 0.f, 0.f, 0.f};
    for (int kk = 0; kk < 32; ++kk) {
        __syncthreads();
        if (tid < 128)
            *(bf16x8*)&Bls[(ko * 32 + rowb) * 8] = rB;
        __syncthreads();
        if (kk + 1 < 32 && tid < 128)
            rB = *(const bf16x8*)(Wr + (size_t)(n0 + rowb) * 1024
                                  + (kk + 1) * 32 + ko * 8);
        bf16x8 af  = *(const bf16x8*)&Als[((kk * 4 + l4) * 32 + fm * 16 + l15) * 8];
        bf16x8 bf_ = *(const bf16x8*)&Bls[(l4 * 32 + nsub + l15) * 8];
        acc = __builtin_amdgcn_mfma_f32_16x16x32_bf16(af, bf_, acc, 0, 0, 0);
    }

    // epilogue: D row r -> b = fm*16 + l4*4 + r ; col -> n' = n0+nsub+l15
    const int n_ = n0 + nsub + l15;
    const int q  = n_ >> 2, cc = n_ & 3;
    float gate[4];
#pragma unroll
    for (int r = 0; r < 4; ++r) {
        int b = fm * 16 + l4 * 4 + r;
        gate[r] = acc[r] + preT[(size_t)b * (TC * G_) + n_];
    }
#pragma unroll
    for (int r = 0; r < 4; ++r) {
        const int srcB = lane & ~3;
        float gi = __shfl(gate[r], srcB + 0, 64);
        float gf = __shfl(gate[r], srcB + 1, 64);
        float gg = __shfl(gate[r], srcB + 2, 64);
        float go = __shfl(gate[r], srcB + 3, 64);
        if (cc == 0) {
            int b = fm * 16 + l4 * 4 + r;
            float i_ = 1.f / (1.f + expf(-gi));
            float f_ = 1.f / (1.f + expf(-gf));
            float g_ = tanhf(gg);
            float o_ = 1.f / (1.f + expf(-go));
            float cn = f_ * cst[b * Q_ + q] + i_ * g_;
            cst[b * Q_ + q] = cn;
            float h = o_ * tanhf(cn);
            hout[(size_t)b * houtS + q] = f2bf(h);
            if (yf) yf[(size_t)b * (T_ * Q_) + q] = h;
        }
    }
}

// ---------------------------------------------------------------------------
// final h from y1[t=511]; c from c1
__global__ void copy_hc(const float* __restrict__ outy,
                        const float* __restrict__ c,
                        float* __restrict__ dst)
{
    int i = blockIdx.x * blockDim.x + threadIdx.x;   // 0..65535
    if (i < 32768) {
        int b = i >> 10, q = i & 1023;
        dst[i] = outy[((size_t)b * T_ + (T_ - 1)) * Q_ + q];
    } else {
        dst[i] = c[i - 32768];
    }
}

// ---------------------------------------------------------------------------
extern "C" void kernel_launch(void* const* d_in, const int* in_sizes, int n_in,
                              void* d_out, int out_size, void* d_ws, size_t ws_size,
                              hipStream_t stream)
{
    const float* x    = (const float*)d_in[0];
    const float* wih0 = (const float*)d_in[1];
    const float* whh0 = (const float*)d_in[2];
    const float* bih0 = (const float*)d_in[3];
    const float* bhh0 = (const float*)d_in[4];
    const float* wih1 = (const float*)d_in[5];
    const float* whh1 = (const float*)d_in[6];
    const float* bih1 = (const float*)d_in[7];
    const float* bhh1 = (const float*)d_in[8];
    float* out = (float*)d_out;   // y1 [32,512,1024] ++ h[32,1024] ++ c[32,1024]
    float* ws  = (float*)d_ws;

    float* pre0 = ws;                                            // 4,194,304 f
    float* pre1 = ws + 4194304;                                  // 4,194,304 f
    unsigned short* xbfc  = (unsigned short*)(ws + 8388608);     // 262,144 f
    unsigned short* wih0b = (unsigned short*)(ws + 8650752);     // 1,048,576 f
    unsigned short* wih1b = (unsigned short*)(ws + 9699328);     // 2,097,152 f
    unsigned short* whh0b = (unsigned short*)(ws + 11796480);    // 2,097,152 f
    unsigned short* whh1b = (unsigned short*)(ws + 13893632);    // 2,097,152 f
    unsigned short* y0cb  = (unsigned short*)(ws + 15990784);    // 524,288 f
    float* biasp0 = ws + 16515072;                               // 4,096 f
    float* biasp1 = ws + 16519168;                               // 4,096 f
    float* st     = ws + 16523264;
    float* c0 = st;                                   // 32,768 f
    float* c1 = st + 32768;                           // 32,768 f
    unsigned short* hinit0 = (unsigned short*)(st + 65536);   // 16,384 f (zeros)
    unsigned short* h1bf0  = (unsigned short*)(st + 81920);   // 16,384 f
    unsigned short* h1bf1  = (unsigned short*)(st + 98304);   // 16,384 f
    // total ws = 16,637,952 floats (~66.6 MB)

    // zero c0, c1, hinit0, h1bf0 (98304 floats)
    hipLaunchKernelGGL(zero_kernel, dim3(384), dim3(256), 0, stream, st, 98304);

    // weight/bias conversions (permuted rows n' = q*4+cc)
    hipLaunchKernelGGL(convert_permute, dim3(2048), dim3(256), 0, stream,
                       wih0, wih0b, 512, 7);
    hipLaunchKernelGGL(convert_permute, dim3(4096), dim3(256), 0, stream,
                       wih1, wih1b, 1024, 8);
    hipLaunchKernelGGL(convert_permute, dim3(4096), dim3(256), 0, stream,
                       whh0, whh0b, 1024, 8);
    hipLaunchKernelGGL(convert_permute, dim3(4096), dim3(256), 0, stream,
                       whh1, whh1b, 1024, 8);
    hipLaunchKernelGGL(permute_bias, dim3(16), dim3(256), 0, stream,
                       bih0, bhh0, biasp0);
    hipLaunchKernelGGL(permute_bias, dim3(16), dim3(256), 0, stream,
                       bih1, bhh1, biasp1);

    // software-pipelined supersteps: layer0 chunk s || layer1 chunk s-1
    for (int s = 0; s <= NCHUNK; ++s) {
        if (s < NCHUNK) {
            hipLaunchKernelGGL(convert_x_chunk, dim3(512), dim3(256), 0, stream,
                               x, xbfc, s * TC);
            hipLaunchKernelGGL(gemm_bf16, dim3(32, 8), dim3(256), 0, stream,
                               xbfc, wih0b, biasp0, pre0, 512);
        }
        if (s >= 1) {
            hipLaunchKernelGGL(gemm_bf16, dim3(32, 8), dim3(256), 0, stream,
                               y0cb, wih1b, biasp1, pre1, 1024);
        }
        for (int tt = 0; tt < TC; ++tt) {
            // slot 0: layer 0, chunk s
            const unsigned short* W0 = (s < NCHUNK) ? whh0b : nullptr;
            const float* p0 = pre0 + tt * G_;
            const unsigned short* h0in; int h0S;
            if (s == 0 && tt == 0)      { h0in = hinit0;              h0S = 1024; }
            else if (tt == 0)           { h0in = y0cb + 31 * 1024;    h0S = TC * 1024; }
            else                        { h0in = y0cb + (tt-1) * 1024; h0S = TC * 1024; }
            unsigned short* h0out = y0cb + tt * 1024;   // stride TC*1024

            // slot 1: layer 1, chunk s-1 (global t1)
            const unsigned short* W1 = (s >= 1) ? whh1b : nullptr;
            int t1 = (s >= 1) ? (s - 1) * TC + tt : 0;
            const float* p1 = pre1 + tt * G_;
            const unsigned short* h1in = (t1 & 1) ? h1bf1 : h1bf0;
            unsigned short* h1out      = (t1 & 1) ? h1bf0 : h1bf1;
            float* y1 = out + (size_t)t1 * Q_;          // stride T_*Q_ per b

            hipLaunchKernelGGL(lstm_step_mfma, dim3(256), dim3(256), 0, stream,
                               W0, p0, h0in, h0S, h0out, TC * 1024, c0, (float*)nullptr,
                               W1, p1, h1in, 1024, h1out, 1024, c1, y1);
        }
    }

    // final (h, c)
    hipLaunchKernelGGL(copy_hc, dim3(256), dim3(256), 0, stream,
                       out, c1, out + 16777216);
}